// Round 5
// baseline (232.237 us; speedup 1.0000x reference)
//
#include <hip/hip_runtime.h>

#define NN 64000
#define NG 512
#define NPG 125
#define DIM 128
#define NC 10
#define SHID 69
#define NF 16
#define PHID 8
#define W1PAD 72   // 69 padded to 72 floats -> every row 16B-aligned in LDS
#define ELPAD 132  // E rows padded 128->132 -> bank-spread for row-wise float4 reads

// output float offsets (concatenated tuple, row-major)
#define OFF_PRED1 0
#define OFF_PRED2 1024
#define OFF_IND   2048
#define OFF_S     2560
#define OFF_E     642560
#define OFF_Q     1297920

// ---------------- threefry2x32 (JAX-exact, key = (0, 42)) ----------------
__device__ __forceinline__ unsigned rotl32(unsigned x, int r) {
    return (x << r) | (x >> (32 - r));
}

__device__ __forceinline__ void threefry_0_42(unsigned x0, unsigned x1,
                                              unsigned& o0, unsigned& o1) {
    const unsigned k0 = 0u, k1 = 42u;
    const unsigned k2 = k0 ^ k1 ^ 0x1BD11BDAu;
    unsigned ks[3] = {k0, k1, k2};
    const int R0[4] = {13, 15, 26, 6};
    const int R1[4] = {17, 29, 16, 24};
    x0 += k0; x1 += k1;
    #pragma unroll
    for (int i = 0; i < 5; i++) {
        const int* R = (i & 1) ? R1 : R0;
        #pragma unroll
        for (int r = 0; r < 4; r++) {
            x0 += x1;
            x1 = rotl32(x1, R[r]);
            x1 ^= x0;
        }
        x0 += ks[(i + 1) % 3];
        x1 += ks[(i + 2) % 3] + (unsigned)(i + 1);
    }
    o0 = x0; o1 = x1;
}

// jax_threefry_partitionable: element i -> counter (0, i); bits = o0 ^ o1. (verified R2)
__device__ __forceinline__ unsigned random_bits_partitionable(unsigned i) {
    unsigned o0, o1;
    threefry_0_42(0u, i, o0, o1);
    return o0 ^ o1;
}

__device__ __forceinline__ float gumbel_from_bits(unsigned bits) {
    float f = __uint_as_float((bits >> 9) | 0x3f800000u) - 1.0f;  // [0,1)
    if (f <= 0.0f) f = 1.1754943508222875e-38f;                   // minval=tiny
    return -logf(-logf(f));
}

// ---------------- K1: per-node MLP 128->69(relu)->10 + softmax ----------------
// Weights staged in LDS; uniform ds_read broadcast. Only j-loops unrolled so
// t[69] has static indices everywhere -> stays in VGPRs (512 budget at 256,1).
__global__ __launch_bounds__(256, 1) void k_node_mlp(
    const float* __restrict__ H, const float* __restrict__ w1,
    const float* __restrict__ b1, const float* __restrict__ w2,
    const float* __restrict__ b2, float* __restrict__ S) {
    __shared__ __align__(16) float w1l[128 * W1PAD];  // 36864 B
    __shared__ __align__(16) float w2l[SHID * 12];    // 3312 B
    __shared__ float b1l[SHID];
    __shared__ float b2l[NC];
    int tid = threadIdx.x;

    for (int i = tid; i < 128 * SHID; i += 256) {
        int k = i / SHID, j = i - k * SHID;
        w1l[k * W1PAD + j] = w1[i];
    }
    for (int i = tid; i < SHID * NC; i += 256) {
        int j = i / NC, c = i - j * NC;
        w2l[j * 12 + c] = w2[i];
    }
    if (tid < SHID) b1l[tid] = b1[tid];
    if (tid < NC) b2l[tid] = b2[tid];
    __syncthreads();

    int n = blockIdx.x * 256 + tid;  // exact: 64000 = 250*256
    const float4* H4 = (const float4*)(H + (size_t)n * DIM);

    float t[SHID];
    #pragma unroll
    for (int j = 0; j < SHID; j++) t[j] = b1l[j];

    #pragma unroll 2
    for (int k4 = 0; k4 < 32; k4++) {
        float4 h4 = H4[k4];
        float hs[4] = {h4.x, h4.y, h4.z, h4.w};
        #pragma unroll
        for (int kk = 0; kk < 4; kk++) {
            float hk = hs[kk];
            const float* wr = &w1l[(k4 * 4 + kk) * W1PAD];  // uniform -> broadcast b128
            #pragma unroll
            for (int j = 0; j < SHID; j++) t[j] = fmaf(hk, wr[j], t[j]);
        }
    }

    float lg[NC];
    #pragma unroll
    for (int c = 0; c < NC; c++) lg[c] = b2l[c];
    #pragma unroll
    for (int j = 0; j < SHID; j++) {
        float tr = fmaxf(t[j], 0.0f);
        #pragma unroll
        for (int c = 0; c < NC; c++) lg[c] = fmaf(tr, w2l[j * 12 + c], lg[c]);
    }

    float m = lg[0];
    #pragma unroll
    for (int c = 1; c < NC; c++) m = fmaxf(m, lg[c]);
    float e[NC], s = 0.0f;
    #pragma unroll
    for (int c = 0; c < NC; c++) { e[c] = expf(lg[c] - m); s += e[c]; }
    float inv = 1.0f / s;
    float2* Sp2 = (float2*)(S + (size_t)n * NC);  // n*40 B: 8-aligned
    #pragma unroll
    for (int c = 0; c < 5; c++)
        Sp2[c] = make_float2(e[2 * c] * inv, e[2 * c + 1] * inv);
}

// ---------------- K2: fused E + tail (corr, pred1, sample, Q, fm, pred2) ----------------
// Block = graph, 128 threads (thread = d). S_g staged in LDS (no scalar-load
// barriers); E kept in LDS (padded) for the in-block tail on wave 0.
__global__ __launch_bounds__(128, 1) void k_E_tail(
    const float* __restrict__ H, const float* __restrict__ S,
    const float* __restrict__ wf, const float* __restrict__ bf,
    const int* __restrict__ targets,
    const float* __restrict__ p1, const float* __restrict__ pb1,
    const float* __restrict__ p2, const float* __restrict__ pb2,
    const float* __restrict__ ci, const float* __restrict__ cr,
    float* __restrict__ E, float* __restrict__ pred1, float* __restrict__ pred2,
    float* __restrict__ ind, float* __restrict__ Q) {
    __shared__ float Sl[NPG * NC];                 // 5000 B
    __shared__ __align__(16) float El[NC * ELPAD]; // 5280 B
    __shared__ float fmbuf[NC];
    int g = blockIdx.x, tid = threadIdx.x;

    const float* Sg = S + (size_t)g * NPG * NC;
    for (int i = tid; i < NPG * NC; i += 128) Sl[i] = Sg[i];
    __syncthreads();

    const float* Hg = H + (size_t)g * NPG * DIM + tid;
    float acc[NC] = {0.f, 0.f, 0.f, 0.f, 0.f, 0.f, 0.f, 0.f, 0.f, 0.f};
    #pragma unroll 5
    for (int nn = 0; nn < NPG; nn++) {
        float h = Hg[(size_t)nn * DIM];
        #pragma unroll
        for (int c = 0; c < NC; c++) acc[c] = fmaf(Sl[nn * NC + c], h, acc[c]);
    }
    float* Eo = E + (size_t)g * (NC * DIM) + tid;
    #pragma unroll
    for (int c = 0; c < NC; c++) {
        Eo[c * DIM] = acc[c];
        El[c * ELPAD + tid] = acc[c];
    }
    __syncthreads();

    const float2* wf2 = (const float2*)wf;
    int l = tid;
    int samp = 0;
    float corr_lf = 0.f;

    if (tid < 64) {
        // ---- corr: lane l<32 computes corr[i=l>>4][f=l&15] ----
        if (l < 32) {
            int i = l >> 4, f = l & 15;
            float a = ci[f], b = ci[NF + f];
            float mm = fmaxf(a, b);
            float ea = expf(a - mm), eb = expf(b - mm);
            float inter = expf(ci[i * NF + f] - mm) / (ea + eb);
            float mi = -1e30f;
            for (int j = 0; j < NF; j++) mi = fmaxf(mi, cr[i * NF + j]);
            float ri = 0.f;
            for (int j = 0; j < NF; j++) ri += expf(cr[i * NF + j] - mi);
            float intra = expf(cr[i * NF + f] - mi) / ri;
            corr_lf = inter * intra;
        }

        // ---- phase 1: pred1 + softmax + gumbel sample + ind ----
        float a0 = 0.f, a1 = 0.f;
        #pragma unroll
        for (int i = 0; i < 20; i++) {
            int idx = i * 64 + l;
            float e = El[(idx >> 7) * ELPAD + (idx & 127)];
            float2 w = wf2[idx];
            a0 = fmaf(e, w.x, a0);
            a1 = fmaf(e, w.y, a1);
        }
        #pragma unroll
        for (int off = 32; off > 0; off >>= 1) {
            a0 += __shfl_down(a0, off);
            a1 += __shfl_down(a1, off);
        }
        if (l == 0) {
            float y0 = a0 + bf[0], y1 = a1 + bf[1];
            pred1[g * 2] = y0;
            pred1[g * 2 + 1] = y1;
            float m = fmaxf(y0, y1);
            float e0 = expf(y0 - m), e1 = expf(y1 - m), s = e0 + e1;
            float p0 = e0 / s, pp1 = e1 / s;
            float g0 = gumbel_from_bits(random_bits_partitionable(2 * g));
            float g1 = gumbel_from_bits(random_bits_partitionable(2 * g + 1));
            float l0 = logf(p0 + 1e-12f) + g0;
            float l1 = logf(pp1 + 1e-12f) + g1;
            samp = (l1 > l0) ? 1 : 0;
            ind[g] = (samp == targets[g]) ? 1.0f : 0.0f;
        }
        samp = __shfl(samp, 0);

        // ---- phase 2: Q-MLP (128->8 relu ->16 softmax) + feature_mask ----
        if (l < 40) {
            int p = l >> 2, s = l & 3;
            float ua = pb1[2 * s], ub = pb1[2 * s + 1];
            const float4* E4 = (const float4*)&El[p * ELPAD];  // p*132: bank-spread
            #pragma unroll 4
            for (int k4 = 0; k4 < 32; k4++) {
                float4 e4 = E4[k4];
                float es[4] = {e4.x, e4.y, e4.z, e4.w};
                #pragma unroll
                for (int kk = 0; kk < 4; kk++) {
                    int k = k4 * 4 + kk;
                    ua = fmaf(es[kk], p1[k * PHID + 2 * s], ua);
                    ub = fmaf(es[kk], p1[k * PHID + 2 * s + 1], ub);
                }
            }
            ua = fmaxf(ua, 0.f);
            ub = fmaxf(ub, 0.f);
            float v[NF];
            #pragma unroll
            for (int f = 0; f < NF; f++) {
                v[f] = pb2[f] * 0.25f;  // bias split: reduce over 4 lanes adds it once
                v[f] = fmaf(ua, p2[(2 * s) * NF + f], v[f]);
                v[f] = fmaf(ub, p2[(2 * s + 1) * NF + f], v[f]);
            }
            #pragma unroll
            for (int f = 0; f < NF; f++) {
                v[f] += __shfl_xor(v[f], 1);
                v[f] += __shfl_xor(v[f], 2);
            }
            float m = v[0];
            #pragma unroll
            for (int f = 1; f < NF; f++) m = fmaxf(m, v[f]);
            float ssum = 0.f, q[NF];
            #pragma unroll
            for (int f = 0; f < NF; f++) { q[f] = expf(v[f] - m); ssum += q[f]; }
            float inv = 1.0f / ssum;
            #pragma unroll
            for (int f = 0; f < NF; f++) q[f] *= inv;
            float* Qo = Q + ((size_t)g * NC + p) * NF;
            ((float4*)Qo)[s] = make_float4(q[s * 4], q[s * 4 + 1], q[s * 4 + 2], q[s * 4 + 3]);
            float fmv = 0.f;
            #pragma unroll
            for (int f = 0; f < NF; f++) {
                float cv = __shfl(corr_lf, samp * NF + f);
                fmv = fmaf(q[f], cv, fmv);
            }
            if (s == 0) fmbuf[p] = fmv;
        }
    }
    __syncthreads();  // all 128 threads reach this

    if (tid < 64) {
        // ---- phase 3: pred2 ----
        float b0 = 0.f, b1acc = 0.f;
        #pragma unroll
        for (int i = 0; i < 20; i++) {
            int idx = i * 64 + l;
            float e = El[(idx >> 7) * ELPAD + (idx & 127)] * fmbuf[idx >> 7];
            float2 w = wf2[idx];
            b0 = fmaf(e, w.x, b0);
            b1acc = fmaf(e, w.y, b1acc);
        }
        #pragma unroll
        for (int off = 32; off > 0; off >>= 1) {
            b0 += __shfl_down(b0, off);
            b1acc += __shfl_down(b1acc, off);
        }
        if (l == 0) {
            pred2[g * 2] = b0 + bf[0];
            pred2[g * 2 + 1] = b1acc + bf[1];
        }
    }
}

extern "C" void kernel_launch(void* const* d_in, const int* in_sizes, int n_in,
                              void* d_out, int out_size, void* d_ws, size_t ws_size,
                              hipStream_t stream) {
    const float* H       = (const float*)d_in[0];
    // d_in[1] = batch (implied by n/125, unused)
    const int*   targets = (const int*)d_in[2];
    const float* w1      = (const float*)d_in[3];
    const float* b1      = (const float*)d_in[4];
    const float* w2      = (const float*)d_in[5];
    const float* b2      = (const float*)d_in[6];
    const float* wf      = (const float*)d_in[7];
    const float* bf      = (const float*)d_in[8];
    const float* p1      = (const float*)d_in[9];
    const float* pb1     = (const float*)d_in[10];
    const float* p2      = (const float*)d_in[11];
    const float* pb2     = (const float*)d_in[12];
    const float* ci      = (const float*)d_in[13];
    const float* cr      = (const float*)d_in[14];

    float* out   = (float*)d_out;
    float* pred1 = out + OFF_PRED1;
    float* pred2 = out + OFF_PRED2;
    float* ind   = out + OFF_IND;
    float* S     = out + OFF_S;
    float* E     = out + OFF_E;
    float* Q     = out + OFF_Q;

    k_node_mlp<<<NN / 256, 256, 0, stream>>>(H, w1, b1, w2, b2, S);
    k_E_tail<<<NG, 128, 0, stream>>>(H, S, wf, bf, targets, p1, pb1, p2, pb2,
                                     ci, cr, E, pred1, pred2, ind, Q);
}

// Round 6
// 185.306 us; speedup vs baseline: 1.2533x; 1.2533x over previous
//
#include <hip/hip_runtime.h>

#define NN 64000
#define NG 512
#define NPG 125
#define DIM 128
#define NC 10
#define SHID 69
#define NF 16
#define PHID 8
#define ELPAD 132  // E rows padded 128->132 in LDS

// output float offsets (concatenated tuple, row-major)
#define OFF_PRED1 0
#define OFF_PRED2 1024
#define OFF_IND   2048
#define OFF_S     2560
#define OFF_E     642560
#define OFF_Q     1297920

// ---------------- threefry2x32 (JAX-exact, key = (0, 42)) ----------------
__device__ __forceinline__ unsigned rotl32(unsigned x, int r) {
    return (x << r) | (x >> (32 - r));
}

__device__ __forceinline__ void threefry_0_42(unsigned x0, unsigned x1,
                                              unsigned& o0, unsigned& o1) {
    const unsigned k0 = 0u, k1 = 42u;
    const unsigned k2 = k0 ^ k1 ^ 0x1BD11BDAu;
    unsigned ks[3] = {k0, k1, k2};
    const int R0[4] = {13, 15, 26, 6};
    const int R1[4] = {17, 29, 16, 24};
    x0 += k0; x1 += k1;
    #pragma unroll
    for (int i = 0; i < 5; i++) {
        const int* R = (i & 1) ? R1 : R0;
        #pragma unroll
        for (int r = 0; r < 4; r++) {
            x0 += x1;
            x1 = rotl32(x1, R[r]);
            x1 ^= x0;
        }
        x0 += ks[(i + 1) % 3];
        x1 += ks[(i + 2) % 3] + (unsigned)(i + 1);
    }
    o0 = x0; o1 = x1;
}

// jax_threefry_partitionable: element i -> counter (0, i); bits = o0 ^ o1. (verified R2)
__device__ __forceinline__ unsigned random_bits_partitionable(unsigned i) {
    unsigned o0, o1;
    threefry_0_42(0u, i, o0, o1);
    return o0 ^ o1;
}

__device__ __forceinline__ float gumbel_from_bits(unsigned bits) {
    float f = __uint_as_float((bits >> 9) | 0x3f800000u) - 1.0f;  // [0,1)
    if (f <= 0.0f) f = 1.1754943508222875e-38f;                   // minval=tiny
    return -logf(-logf(f));
}

// ---------------- K1: per-node MLP 128->69(relu)->10 + softmax ----------------
// t split into 3 small arrays (24/24/21) with static-index unrolled loops ->
// SROA-promotable to VGPRs. Weights read through wave-uniform pointers ->
// compiler emits s_load; fma takes the SGPR operand directly.
__global__ __launch_bounds__(64, 2) void k_node_mlp(
    const float* __restrict__ H, const float* __restrict__ w1,
    const float* __restrict__ b1, const float* __restrict__ w2,
    const float* __restrict__ b2, float* __restrict__ S) {
    int n = blockIdx.x * 64 + threadIdx.x;  // exact: 64000 = 1000*64
    const float4* H4 = (const float4*)(H + (size_t)n * DIM);

    float ta[24], tb[24], tc[21];
    #pragma unroll
    for (int j = 0; j < 24; j++) ta[j] = b1[j];
    #pragma unroll
    for (int j = 0; j < 24; j++) tb[j] = b1[24 + j];
    #pragma unroll
    for (int j = 0; j < 21; j++) tc[j] = b1[48 + j];

    #pragma unroll 2
    for (int k4 = 0; k4 < 32; k4++) {
        float4 h4 = H4[k4];
        float hs[4] = {h4.x, h4.y, h4.z, h4.w};
        #pragma unroll
        for (int kk = 0; kk < 4; kk++) {
            float hk = hs[kk];
            const float* wr = w1 + (k4 * 4 + kk) * SHID;  // wave-uniform -> s_load
            #pragma unroll
            for (int j = 0; j < 24; j++) ta[j] = fmaf(hk, wr[j], ta[j]);
            #pragma unroll
            for (int j = 0; j < 24; j++) tb[j] = fmaf(hk, wr[24 + j], tb[j]);
            #pragma unroll
            for (int j = 0; j < 21; j++) tc[j] = fmaf(hk, wr[48 + j], tc[j]);
        }
    }

    float lg[NC];
    #pragma unroll
    for (int c = 0; c < NC; c++) lg[c] = b2[c];
    #pragma unroll
    for (int j = 0; j < 24; j++) {
        float tr = fmaxf(ta[j], 0.0f);
        const float* w2r = w2 + j * NC;  // wave-uniform
        #pragma unroll
        for (int c = 0; c < NC; c++) lg[c] = fmaf(tr, w2r[c], lg[c]);
    }
    #pragma unroll
    for (int j = 0; j < 24; j++) {
        float tr = fmaxf(tb[j], 0.0f);
        const float* w2r = w2 + (24 + j) * NC;
        #pragma unroll
        for (int c = 0; c < NC; c++) lg[c] = fmaf(tr, w2r[c], lg[c]);
    }
    #pragma unroll
    for (int j = 0; j < 21; j++) {
        float tr = fmaxf(tc[j], 0.0f);
        const float* w2r = w2 + (48 + j) * NC;
        #pragma unroll
        for (int c = 0; c < NC; c++) lg[c] = fmaf(tr, w2r[c], lg[c]);
    }

    float m = lg[0];
    #pragma unroll
    for (int c = 1; c < NC; c++) m = fmaxf(m, lg[c]);
    float e[NC], s = 0.0f;
    #pragma unroll
    for (int c = 0; c < NC; c++) { e[c] = expf(lg[c] - m); s += e[c]; }
    float inv = 1.0f / s;
    float2* Sp2 = (float2*)(S + (size_t)n * NC);  // n*40 B: 8-aligned
    #pragma unroll
    for (int c = 0; c < 5; c++)
        Sp2[c] = make_float2(e[2 * c] * inv, e[2 * c + 1] * inv);
}

// ---------------- K2: fused E + tail (corr, pred1, sample, Q, fm, pred2) ----------------
// Block = graph, 128 threads (thread = d). S_g staged in LDS; E kept in LDS
// (padded) for the in-block tail on wave 0. E-loop unrolled x25 for MLP depth.
__global__ __launch_bounds__(128, 1) void k_E_tail(
    const float* __restrict__ H, const float* __restrict__ S,
    const float* __restrict__ wf, const float* __restrict__ bf,
    const int* __restrict__ targets,
    const float* __restrict__ p1, const float* __restrict__ pb1,
    const float* __restrict__ p2, const float* __restrict__ pb2,
    const float* __restrict__ ci, const float* __restrict__ cr,
    float* __restrict__ E, float* __restrict__ pred1, float* __restrict__ pred2,
    float* __restrict__ ind, float* __restrict__ Q) {
    __shared__ float Sl[NPG * NC];                 // 5000 B
    __shared__ __align__(16) float El[NC * ELPAD]; // 5280 B
    __shared__ float fmbuf[NC];
    int g = blockIdx.x, tid = threadIdx.x;

    const float* Sg = S + (size_t)g * NPG * NC;
    for (int i = tid; i < NPG * NC; i += 128) Sl[i] = Sg[i];
    __syncthreads();

    const float* Hg = H + (size_t)g * NPG * DIM + tid;
    float acc[NC] = {0.f, 0.f, 0.f, 0.f, 0.f, 0.f, 0.f, 0.f, 0.f, 0.f};
    #pragma unroll
    for (int nb = 0; nb < NPG; nb += 25) {
        float h[25];
        #pragma unroll
        for (int u = 0; u < 25; u++) h[u] = Hg[(size_t)(nb + u) * DIM];
        #pragma unroll
        for (int u = 0; u < 25; u++) {
            #pragma unroll
            for (int c = 0; c < NC; c++)
                acc[c] = fmaf(Sl[(nb + u) * NC + c], h[u], acc[c]);
        }
    }
    float* Eo = E + (size_t)g * (NC * DIM) + tid;
    #pragma unroll
    for (int c = 0; c < NC; c++) {
        Eo[c * DIM] = acc[c];
        El[c * ELPAD + tid] = acc[c];
    }
    __syncthreads();

    const float2* wf2 = (const float2*)wf;
    int l = tid;
    int samp = 0;
    float corr_lf = 0.f;

    if (tid < 64) {
        // ---- corr: lane l<32 computes corr[i=l>>4][f=l&15] ----
        if (l < 32) {
            int i = l >> 4, f = l & 15;
            float a = ci[f], b = ci[NF + f];
            float mm = fmaxf(a, b);
            float ea = expf(a - mm), eb = expf(b - mm);
            float inter = expf(ci[i * NF + f] - mm) / (ea + eb);
            float mi = -1e30f;
            for (int j = 0; j < NF; j++) mi = fmaxf(mi, cr[i * NF + j]);
            float ri = 0.f;
            for (int j = 0; j < NF; j++) ri += expf(cr[i * NF + j] - mi);
            float intra = expf(cr[i * NF + f] - mi) / ri;
            corr_lf = inter * intra;
        }

        // ---- phase 1: pred1 + softmax + gumbel sample + ind ----
        float a0 = 0.f, a1 = 0.f;
        #pragma unroll
        for (int i = 0; i < 20; i++) {
            int idx = i * 64 + l;
            float e = El[(idx >> 7) * ELPAD + (idx & 127)];
            float2 w = wf2[idx];
            a0 = fmaf(e, w.x, a0);
            a1 = fmaf(e, w.y, a1);
        }
        #pragma unroll
        for (int off = 32; off > 0; off >>= 1) {
            a0 += __shfl_down(a0, off);
            a1 += __shfl_down(a1, off);
        }
        if (l == 0) {
            float y0 = a0 + bf[0], y1 = a1 + bf[1];
            pred1[g * 2] = y0;
            pred1[g * 2 + 1] = y1;
            float m = fmaxf(y0, y1);
            float e0 = expf(y0 - m), e1 = expf(y1 - m), s = e0 + e1;
            float p0 = e0 / s, pp1 = e1 / s;
            float g0 = gumbel_from_bits(random_bits_partitionable(2 * g));
            float g1 = gumbel_from_bits(random_bits_partitionable(2 * g + 1));
            float l0 = logf(p0 + 1e-12f) + g0;
            float l1 = logf(pp1 + 1e-12f) + g1;
            samp = (l1 > l0) ? 1 : 0;
            ind[g] = (samp == targets[g]) ? 1.0f : 0.0f;
        }
        samp = __shfl(samp, 0);

        // ---- phase 2: Q-MLP (128->8 relu ->16 softmax) + feature_mask ----
        if (l < 40) {
            int p = l >> 2, s = l & 3;
            float ua = pb1[2 * s], ub = pb1[2 * s + 1];
            const float4* E4 = (const float4*)&El[p * ELPAD];  // p*132: bank-spread
            #pragma unroll 4
            for (int k4 = 0; k4 < 32; k4++) {
                float4 e4 = E4[k4];
                float es[4] = {e4.x, e4.y, e4.z, e4.w};
                #pragma unroll
                for (int kk = 0; kk < 4; kk++) {
                    int k = k4 * 4 + kk;
                    ua = fmaf(es[kk], p1[k * PHID + 2 * s], ua);
                    ub = fmaf(es[kk], p1[k * PHID + 2 * s + 1], ub);
                }
            }
            ua = fmaxf(ua, 0.f);
            ub = fmaxf(ub, 0.f);
            float v[NF];
            #pragma unroll
            for (int f = 0; f < NF; f++) {
                v[f] = pb2[f] * 0.25f;  // bias split: reduce over 4 lanes adds it once
                v[f] = fmaf(ua, p2[(2 * s) * NF + f], v[f]);
                v[f] = fmaf(ub, p2[(2 * s + 1) * NF + f], v[f]);
            }
            #pragma unroll
            for (int f = 0; f < NF; f++) {
                v[f] += __shfl_xor(v[f], 1);
                v[f] += __shfl_xor(v[f], 2);
            }
            float m = v[0];
            #pragma unroll
            for (int f = 1; f < NF; f++) m = fmaxf(m, v[f]);
            float ssum = 0.f, q[NF];
            #pragma unroll
            for (int f = 0; f < NF; f++) { q[f] = expf(v[f] - m); ssum += q[f]; }
            float inv = 1.0f / ssum;
            #pragma unroll
            for (int f = 0; f < NF; f++) q[f] *= inv;
            float* Qo = Q + ((size_t)g * NC + p) * NF;
            ((float4*)Qo)[s] = make_float4(q[s * 4], q[s * 4 + 1], q[s * 4 + 2], q[s * 4 + 3]);
            float fmv = 0.f;
            #pragma unroll
            for (int f = 0; f < NF; f++) {
                float cv = __shfl(corr_lf, samp * NF + f);
                fmv = fmaf(q[f], cv, fmv);
            }
            if (s == 0) fmbuf[p] = fmv;
        }
    }
    __syncthreads();  // all 128 threads reach this

    if (tid < 64) {
        // ---- phase 3: pred2 ----
        float b0 = 0.f, b1acc = 0.f;
        #pragma unroll
        for (int i = 0; i < 20; i++) {
            int idx = i * 64 + l;
            float e = El[(idx >> 7) * ELPAD + (idx & 127)] * fmbuf[idx >> 7];
            float2 w = wf2[idx];
            b0 = fmaf(e, w.x, b0);
            b1acc = fmaf(e, w.y, b1acc);
        }
        #pragma unroll
        for (int off = 32; off > 0; off >>= 1) {
            b0 += __shfl_down(b0, off);
            b1acc += __shfl_down(b1acc, off);
        }
        if (l == 0) {
            pred2[g * 2] = b0 + bf[0];
            pred2[g * 2 + 1] = b1acc + bf[1];
        }
    }
}

extern "C" void kernel_launch(void* const* d_in, const int* in_sizes, int n_in,
                              void* d_out, int out_size, void* d_ws, size_t ws_size,
                              hipStream_t stream) {
    const float* H       = (const float*)d_in[0];
    // d_in[1] = batch (implied by n/125, unused)
    const int*   targets = (const int*)d_in[2];
    const float* w1      = (const float*)d_in[3];
    const float* b1      = (const float*)d_in[4];
    const float* w2      = (const float*)d_in[5];
    const float* b2      = (const float*)d_in[6];
    const float* wf      = (const float*)d_in[7];
    const float* bf      = (const float*)d_in[8];
    const float* p1      = (const float*)d_in[9];
    const float* pb1     = (const float*)d_in[10];
    const float* p2      = (const float*)d_in[11];
    const float* pb2     = (const float*)d_in[12];
    const float* ci      = (const float*)d_in[13];
    const float* cr      = (const float*)d_in[14];

    float* out   = (float*)d_out;
    float* pred1 = out + OFF_PRED1;
    float* pred2 = out + OFF_PRED2;
    float* ind   = out + OFF_IND;
    float* S     = out + OFF_S;
    float* E     = out + OFF_E;
    float* Q     = out + OFF_Q;

    k_node_mlp<<<NN / 64, 64, 0, stream>>>(H, w1, b1, w2, b2, S);
    k_E_tail<<<NG, 128, 0, stream>>>(H, S, wf, bf, targets, p1, pb1, p2, pb2,
                                     ci, cr, E, pred1, pred2, ind, Q);
}

// Round 7
// 176.530 us; speedup vs baseline: 1.3156x; 1.0497x over previous
//
#include <hip/hip_runtime.h>

#define NN 64000
#define NG 512
#define NPG 125
#define DIM 128
#define NC 10
#define SHID 69
#define NF 16
#define PHID 8
#define W1PAD 72   // w1 rows padded 69->72 floats: 16B-aligned -> ds_read_b128
#define ELPAD 132  // E rows padded 128->132 in LDS

// output float offsets (concatenated tuple, row-major)
#define OFF_PRED1 0
#define OFF_PRED2 1024
#define OFF_IND   2048
#define OFF_S     2560
#define OFF_E     642560
#define OFF_Q     1297920

// ---------------- threefry2x32 (JAX-exact, key = (0, 42)) ----------------
__device__ __forceinline__ unsigned rotl32(unsigned x, int r) {
    return (x << r) | (x >> (32 - r));
}

__device__ __forceinline__ void threefry_0_42(unsigned x0, unsigned x1,
                                              unsigned& o0, unsigned& o1) {
    const unsigned k0 = 0u, k1 = 42u;
    const unsigned k2 = k0 ^ k1 ^ 0x1BD11BDAu;
    unsigned ks[3] = {k0, k1, k2};
    const int R0[4] = {13, 15, 26, 6};
    const int R1[4] = {17, 29, 16, 24};
    x0 += k0; x1 += k1;
    #pragma unroll
    for (int i = 0; i < 5; i++) {
        const int* R = (i & 1) ? R1 : R0;
        #pragma unroll
        for (int r = 0; r < 4; r++) {
            x0 += x1;
            x1 = rotl32(x1, R[r]);
            x1 ^= x0;
        }
        x0 += ks[(i + 1) % 3];
        x1 += ks[(i + 2) % 3] + (unsigned)(i + 1);
    }
    o0 = x0; o1 = x1;
}

// jax_threefry_partitionable: element i -> counter (0, i); bits = o0 ^ o1. (verified R2)
__device__ __forceinline__ unsigned random_bits_partitionable(unsigned i) {
    unsigned o0, o1;
    threefry_0_42(0u, i, o0, o1);
    return o0 ^ o1;
}

__device__ __forceinline__ float gumbel_from_bits(unsigned bits) {
    float f = __uint_as_float((bits >> 9) | 0x3f800000u) - 1.0f;  // [0,1)
    if (f <= 0.0f) f = 1.1754943508222875e-38f;                   // minval=tiny
    return -logf(-logf(f));
}

// ---------------- repetition macros (force named-scalar promotion) ----------------
#define R18(M) M(0) M(1) M(2) M(3) M(4) M(5) M(6) M(7) M(8) M(9) M(10) M(11) M(12) M(13) M(14) M(15) M(16) M(17)
#define R17(M) M(0) M(1) M(2) M(3) M(4) M(5) M(6) M(7) M(8) M(9) M(10) M(11) M(12) M(13) M(14) M(15) M(16)
#define R10(M) M(0) M(1) M(2) M(3) M(4) M(5) M(6) M(7) M(8) M(9)

// ---------------- K1: per-node MLP 128->69(relu)->10 + softmax ----------------
// Wave = 16 nodes x 4 k-quarters (kq = lane>>4). Each lane accumulates its
// 32-k partial for all 69(72) hidden units in 18 named float4s (registers,
// guaranteed). w1 staged once per block in LDS (padded rows, b128 reads,
// broadcast within kq group). Partials combined via shfl_xor(16/32).
// 1000 blocks x 4 waves = 4000 waves -> 4 waves/SIMD latency hiding.
__global__ __launch_bounds__(256, 4) void k_node_mlp(
    const float* __restrict__ H, const float* __restrict__ w1,
    const float* __restrict__ b1, const float* __restrict__ w2,
    const float* __restrict__ b2, float* __restrict__ S) {
    __shared__ __align__(16) float w1l[DIM * W1PAD];  // 36864 B
    int tid = threadIdx.x;

    for (int i = tid; i < DIM * SHID; i += 256) {
        int k = i / SHID, j = i - k * SHID;
        w1l[k * W1PAD + j] = w1[i];
    }
    for (int i = tid; i < DIM * 3; i += 256) {  // zero the pad columns
        int k = i / 3, r = i - 3 * k;
        w1l[k * W1PAD + SHID + r] = 0.0f;
    }
    __syncthreads();

    int l = tid & 63;
    int w = tid >> 6;
    int kq = l >> 4;                              // k-quarter 0..3
    int node = blockIdx.x * 64 + w * 16 + (l & 15);

    #define DECLT(q) float4 t##q = make_float4(0.f, 0.f, 0.f, 0.f);
    R18(DECLT)
    #undef DECLT

    const float* Hp = H + (size_t)node * DIM + kq * 32;
    #define FMAQ(q) { float4 wv = *(const float4*)(wr + 4 * (q)); \
        t##q.x = fmaf(hk, wv.x, t##q.x); t##q.y = fmaf(hk, wv.y, t##q.y); \
        t##q.z = fmaf(hk, wv.z, t##q.z); t##q.w = fmaf(hk, wv.w, t##q.w); }
    #pragma unroll 2
    for (int k4 = 0; k4 < 8; k4++) {
        float4 h4 = *(const float4*)(Hp + k4 * 4);
        int kb = kq * 32 + k4 * 4;
        { const float* wr = &w1l[(kb + 0) * W1PAD]; float hk = h4.x; R18(FMAQ) }
        { const float* wr = &w1l[(kb + 1) * W1PAD]; float hk = h4.y; R18(FMAQ) }
        { const float* wr = &w1l[(kb + 2) * W1PAD]; float hk = h4.z; R18(FMAQ) }
        { const float* wr = &w1l[(kb + 3) * W1PAD]; float hk = h4.w; R18(FMAQ) }
    }
    #undef FMAQ

    // combine the 4 k-quarter partials (lanes n, n+16, n+32, n+48 share a node)
    #define REDQ(q) \
        t##q.x += __shfl_xor(t##q.x, 16); t##q.y += __shfl_xor(t##q.y, 16); \
        t##q.z += __shfl_xor(t##q.z, 16); t##q.w += __shfl_xor(t##q.w, 16); \
        t##q.x += __shfl_xor(t##q.x, 32); t##q.y += __shfl_xor(t##q.y, 32); \
        t##q.z += __shfl_xor(t##q.z, 32); t##q.w += __shfl_xor(t##q.w, 32);
    R18(REDQ)
    #undef REDQ

    // layer 2: lg[c] += relu(t_j + b1_j) * w2[j][c]   (all lanes, redundant x4)
    #define DECLG(c) float lg##c = b2[c];
    R10(DECLG)
    #undef DECLG
    #define L2C(tv, j) { float tr = fmaxf((tv) + b1[(j)], 0.f); \
        lg0 = fmaf(tr, w2[(j) * 10 + 0], lg0); lg1 = fmaf(tr, w2[(j) * 10 + 1], lg1); \
        lg2 = fmaf(tr, w2[(j) * 10 + 2], lg2); lg3 = fmaf(tr, w2[(j) * 10 + 3], lg3); \
        lg4 = fmaf(tr, w2[(j) * 10 + 4], lg4); lg5 = fmaf(tr, w2[(j) * 10 + 5], lg5); \
        lg6 = fmaf(tr, w2[(j) * 10 + 6], lg6); lg7 = fmaf(tr, w2[(j) * 10 + 7], lg7); \
        lg8 = fmaf(tr, w2[(j) * 10 + 8], lg8); lg9 = fmaf(tr, w2[(j) * 10 + 9], lg9); }
    #define L2Q(q) L2C(t##q.x, 4 * (q)) L2C(t##q.y, 4 * (q) + 1) \
                   L2C(t##q.z, 4 * (q) + 2) L2C(t##q.w, 4 * (q) + 3)
    R17(L2Q)
    L2C(t17.x, 68)
    #undef L2Q
    #undef L2C

    // softmax + store (lanes with kq==0 write their node's row)
    float m = fmaxf(fmaxf(fmaxf(lg0, lg1), fmaxf(lg2, lg3)),
                    fmaxf(fmaxf(fmaxf(lg4, lg5), fmaxf(lg6, lg7)), fmaxf(lg8, lg9)));
    float e0 = expf(lg0 - m), e1 = expf(lg1 - m), e2 = expf(lg2 - m),
          e3 = expf(lg3 - m), e4 = expf(lg4 - m), e5 = expf(lg5 - m),
          e6 = expf(lg6 - m), e7 = expf(lg7 - m), e8 = expf(lg8 - m),
          e9 = expf(lg9 - m);
    float ssum = ((e0 + e1) + (e2 + e3)) + ((e4 + e5) + (e6 + e7)) + (e8 + e9);
    float inv = 1.0f / ssum;
    if (kq == 0) {
        float2* Sp2 = (float2*)(S + (size_t)node * NC);
        Sp2[0] = make_float2(e0 * inv, e1 * inv);
        Sp2[1] = make_float2(e2 * inv, e3 * inv);
        Sp2[2] = make_float2(e4 * inv, e5 * inv);
        Sp2[3] = make_float2(e6 * inv, e7 * inv);
        Sp2[4] = make_float2(e8 * inv, e9 * inv);
    }
}

// ---------------- K2: fused E + tail (corr, pred1, sample, Q, fm, pred2) ----------------
// Block = graph, 512 threads = 4 node-quarters x 128 d. Named-scalar accums,
// LDS combine, then the verified tail runs on wave 0 off LDS-resident E.
__global__ __launch_bounds__(512, 2) void k_E_tail(
    const float* __restrict__ H, const float* __restrict__ S,
    const float* __restrict__ wf, const float* __restrict__ bf,
    const int* __restrict__ targets,
    const float* __restrict__ p1, const float* __restrict__ pb1,
    const float* __restrict__ p2, const float* __restrict__ pb2,
    const float* __restrict__ ci, const float* __restrict__ cr,
    float* __restrict__ E, float* __restrict__ pred1, float* __restrict__ pred2,
    float* __restrict__ ind, float* __restrict__ Q) {
    __shared__ float Sl[128 * NC];                 // padded to 128 node rows
    __shared__ float Epart[3 * 128 * NC];          // quarters 1..3 partials
    __shared__ __align__(16) float El[NC * ELPAD];
    __shared__ float fmbuf[NC];
    int g = blockIdx.x, tid = threadIdx.x;

    const float* Sg = S + (size_t)g * NPG * NC;
    for (int i = tid; i < 128 * NC; i += 512) Sl[i] = (i < NPG * NC) ? Sg[i] : 0.0f;
    __syncthreads();

    int q = tid >> 7;       // node quarter 0..3
    int d = tid & 127;
    const float* Hg = H + (size_t)g * NPG * DIM + d;

    #define DECLA(c) float a##c = 0.f;
    R10(DECLA)
    #undef DECLA
    int n0 = q * 32;
    #pragma unroll 8
    for (int i = 0; i < 32; i++) {
        int n = n0 + i;
        int nh = min(n, NPG - 1);               // rows 125..127 have S=0
        float h = Hg[(size_t)nh * DIM];
        #define ACC(c) a##c = fmaf(Sl[n * NC + c], h, a##c);
        R10(ACC)
        #undef ACC
    }
    if (q > 0) {
        float* ep = &Epart[(q - 1) * 128 * NC + d * NC];
        #define STP(c) ep[c] = a##c;
        R10(STP)
        #undef STP
    }
    __syncthreads();
    if (q == 0) {
        const float* e1p = &Epart[d * NC];
        const float* e2p = &Epart[128 * NC + d * NC];
        const float* e3p = &Epart[2 * 128 * NC + d * NC];
        float* Eo = E + (size_t)g * (NC * DIM) + d;
        #define CMB(c) { a##c += e1p[c] + e2p[c] + e3p[c]; \
                         El[c * ELPAD + d] = a##c; Eo[c * DIM] = a##c; }
        R10(CMB)
        #undef CMB
    }
    __syncthreads();

    const float2* wf2 = (const float2*)wf;
    int l = tid;
    int samp = 0;
    float corr_lf = 0.f;

    if (tid < 64) {
        // ---- corr: lane l<32 computes corr[i=l>>4][f=l&15] ----
        if (l < 32) {
            int i = l >> 4, f = l & 15;
            float a = ci[f], b = ci[NF + f];
            float mm = fmaxf(a, b);
            float ea = expf(a - mm), eb = expf(b - mm);
            float inter = expf(ci[i * NF + f] - mm) / (ea + eb);
            float mi = -1e30f;
            for (int j = 0; j < NF; j++) mi = fmaxf(mi, cr[i * NF + j]);
            float ri = 0.f;
            for (int j = 0; j < NF; j++) ri += expf(cr[i * NF + j] - mi);
            float intra = expf(cr[i * NF + f] - mi) / ri;
            corr_lf = inter * intra;
        }

        // ---- phase 1: pred1 + softmax + gumbel sample + ind ----
        float a0 = 0.f, a1 = 0.f;
        #pragma unroll
        for (int i = 0; i < 20; i++) {
            int idx = i * 64 + l;
            float e = El[(idx >> 7) * ELPAD + (idx & 127)];
            float2 w = wf2[idx];
            a0 = fmaf(e, w.x, a0);
            a1 = fmaf(e, w.y, a1);
        }
        #pragma unroll
        for (int off = 32; off > 0; off >>= 1) {
            a0 += __shfl_down(a0, off);
            a1 += __shfl_down(a1, off);
        }
        if (l == 0) {
            float y0 = a0 + bf[0], y1 = a1 + bf[1];
            pred1[g * 2] = y0;
            pred1[g * 2 + 1] = y1;
            float m = fmaxf(y0, y1);
            float e0 = expf(y0 - m), e1 = expf(y1 - m), s = e0 + e1;
            float p0 = e0 / s, pp1 = e1 / s;
            float g0 = gumbel_from_bits(random_bits_partitionable(2 * g));
            float g1 = gumbel_from_bits(random_bits_partitionable(2 * g + 1));
            float l0 = logf(p0 + 1e-12f) + g0;
            float l1 = logf(pp1 + 1e-12f) + g1;
            samp = (l1 > l0) ? 1 : 0;
            ind[g] = (samp == targets[g]) ? 1.0f : 0.0f;
        }
        samp = __shfl(samp, 0);

        // ---- phase 2: Q-MLP (128->8 relu ->16 softmax) + feature_mask ----
        if (l < 40) {
            int p = l >> 2, s = l & 3;
            float ua = pb1[2 * s], ub = pb1[2 * s + 1];
            const float4* E4 = (const float4*)&El[p * ELPAD];
            #pragma unroll 4
            for (int k4 = 0; k4 < 32; k4++) {
                float4 e4 = E4[k4];
                float es[4] = {e4.x, e4.y, e4.z, e4.w};
                #pragma unroll
                for (int kk = 0; kk < 4; kk++) {
                    int k = k4 * 4 + kk;
                    ua = fmaf(es[kk], p1[k * PHID + 2 * s], ua);
                    ub = fmaf(es[kk], p1[k * PHID + 2 * s + 1], ub);
                }
            }
            ua = fmaxf(ua, 0.f);
            ub = fmaxf(ub, 0.f);
            float v[NF];
            #pragma unroll
            for (int f = 0; f < NF; f++) {
                v[f] = pb2[f] * 0.25f;  // bias split: reduce over 4 lanes adds it once
                v[f] = fmaf(ua, p2[(2 * s) * NF + f], v[f]);
                v[f] = fmaf(ub, p2[(2 * s + 1) * NF + f], v[f]);
            }
            #pragma unroll
            for (int f = 0; f < NF; f++) {
                v[f] += __shfl_xor(v[f], 1);
                v[f] += __shfl_xor(v[f], 2);
            }
            float m = v[0];
            #pragma unroll
            for (int f = 1; f < NF; f++) m = fmaxf(m, v[f]);
            float ssum = 0.f, qv[NF];
            #pragma unroll
            for (int f = 0; f < NF; f++) { qv[f] = expf(v[f] - m); ssum += qv[f]; }
            float inv = 1.0f / ssum;
            #pragma unroll
            for (int f = 0; f < NF; f++) qv[f] *= inv;
            float* Qo = Q + ((size_t)g * NC + p) * NF;
            ((float4*)Qo)[s] = make_float4(qv[s * 4], qv[s * 4 + 1], qv[s * 4 + 2], qv[s * 4 + 3]);
            float fmv = 0.f;
            #pragma unroll
            for (int f = 0; f < NF; f++) {
                float cv = __shfl(corr_lf, samp * NF + f);
                fmv = fmaf(qv[f], cv, fmv);
            }
            if (s == 0) fmbuf[p] = fmv;
        }
    }
    __syncthreads();

    if (tid < 64) {
        // ---- phase 3: pred2 ----
        float b0 = 0.f, b1acc = 0.f;
        #pragma unroll
        for (int i = 0; i < 20; i++) {
            int idx = i * 64 + l;
            float e = El[(idx >> 7) * ELPAD + (idx & 127)] * fmbuf[idx >> 7];
            float2 w = wf2[idx];
            b0 = fmaf(e, w.x, b0);
            b1acc = fmaf(e, w.y, b1acc);
        }
        #pragma unroll
        for (int off = 32; off > 0; off >>= 1) {
            b0 += __shfl_down(b0, off);
            b1acc += __shfl_down(b1acc, off);
        }
        if (l == 0) {
            pred2[g * 2] = b0 + bf[0];
            pred2[g * 2 + 1] = b1acc + bf[1];
        }
    }
}

extern "C" void kernel_launch(void* const* d_in, const int* in_sizes, int n_in,
                              void* d_out, int out_size, void* d_ws, size_t ws_size,
                              hipStream_t stream) {
    const float* H       = (const float*)d_in[0];
    // d_in[1] = batch (implied by n/125, unused)
    const int*   targets = (const int*)d_in[2];
    const float* w1      = (const float*)d_in[3];
    const float* b1      = (const float*)d_in[4];
    const float* w2      = (const float*)d_in[5];
    const float* b2      = (const float*)d_in[6];
    const float* wf      = (const float*)d_in[7];
    const float* bf      = (const float*)d_in[8];
    const float* p1      = (const float*)d_in[9];
    const float* pb1     = (const float*)d_in[10];
    const float* p2      = (const float*)d_in[11];
    const float* pb2     = (const float*)d_in[12];
    const float* ci      = (const float*)d_in[13];
    const float* cr      = (const float*)d_in[14];

    float* out   = (float*)d_out;
    float* pred1 = out + OFF_PRED1;
    float* pred2 = out + OFF_PRED2;
    float* ind   = out + OFF_IND;
    float* S     = out + OFF_S;
    float* E     = out + OFF_E;
    float* Q     = out + OFF_Q;

    k_node_mlp<<<NN / 64, 256, 0, stream>>>(H, w1, b1, w2, b2, S);
    k_E_tail<<<NG, 512, 0, stream>>>(H, S, wf, bf, targets, p1, pb1, p2, pb2,
                                     ci, cr, E, pred1, pred2, ind, Q);
}

// Round 8
// 138.514 us; speedup vs baseline: 1.6766x; 1.2745x over previous
//
#include <hip/hip_runtime.h>

#define NN 64000
#define NG 512
#define NPG 125
#define DIM 128
#define NC 10
#define SHID 69
#define NF 16
#define PHID 8
#define ELPAD 132  // E rows padded 128->132 in LDS

// output float offsets (concatenated tuple, row-major)
#define OFF_PRED1 0
#define OFF_PRED2 1024
#define OFF_IND   2048
#define OFF_S     2560
#define OFF_E     642560
#define OFF_Q     1297920

// ---------------- threefry2x32 (JAX-exact, key = (0, 42)) ----------------
__device__ __forceinline__ unsigned rotl32(unsigned x, int r) {
    return (x << r) | (x >> (32 - r));
}

__device__ __forceinline__ void threefry_0_42(unsigned x0, unsigned x1,
                                              unsigned& o0, unsigned& o1) {
    const unsigned k0 = 0u, k1 = 42u;
    const unsigned k2 = k0 ^ k1 ^ 0x1BD11BDAu;
    unsigned ks[3] = {k0, k1, k2};
    const int R0[4] = {13, 15, 26, 6};
    const int R1[4] = {17, 29, 16, 24};
    x0 += k0; x1 += k1;
    #pragma unroll
    for (int i = 0; i < 5; i++) {
        const int* R = (i & 1) ? R1 : R0;
        #pragma unroll
        for (int r = 0; r < 4; r++) {
            x0 += x1;
            x1 = rotl32(x1, R[r]);
            x1 ^= x0;
        }
        x0 += ks[(i + 1) % 3];
        x1 += ks[(i + 2) % 3] + (unsigned)(i + 1);
    }
    o0 = x0; o1 = x1;
}

// jax_threefry_partitionable: element i -> counter (0, i); bits = o0 ^ o1. (verified R2)
__device__ __forceinline__ unsigned random_bits_partitionable(unsigned i) {
    unsigned o0, o1;
    threefry_0_42(0u, i, o0, o1);
    return o0 ^ o1;
}

__device__ __forceinline__ float gumbel_from_bits(unsigned bits) {
    float f = __uint_as_float((bits >> 9) | 0x3f800000u) - 1.0f;  // [0,1)
    if (f <= 0.0f) f = 1.1754943508222875e-38f;                   // minval=tiny
    return -logf(-logf(f));
}

// ---------------- repetition macros (named scalars, no arrays) ----------------
#define R24(M) M(0) M(1) M(2) M(3) M(4) M(5) M(6) M(7) M(8) M(9) M(10) M(11) \
               M(12) M(13) M(14) M(15) M(16) M(17) M(18) M(19) M(20) M(21) M(22) M(23)
#define R10(M) M(0) M(1) M(2) M(3) M(4) M(5) M(6) M(7) M(8) M(9)

// ---------------- K1: per-node MLP 128->69(relu)->10 + softmax ----------------
// 3 waves per 64-node group; wave w owns hidden slice of 24 (last: 21 valid).
// 24 named accumulators/thread (~60 live regs, cap 170). Weights via
// readfirstlane-uniform pointers -> contiguous s_load runs (scalar cache).
// Layer-2 partials combined through 7.7 KB LDS. 3000 waves ~= 3/SIMD.
__global__ __launch_bounds__(192, 3) void k_node_mlp(
    const float* __restrict__ H, const float* __restrict__ w1,
    const float* __restrict__ b1, const float* __restrict__ w2,
    const float* __restrict__ b2, float* __restrict__ S) {
    __shared__ float red[NC * 3 * 64];  // [c][wave][lane]
    int tid = threadIdx.x;
    int lane = tid & 63;
    int wu = __builtin_amdgcn_readfirstlane(tid >> 6);  // 0..2, provably uniform
    int jbase = wu * 24;
    int node = blockIdx.x * 64 + lane;

    const float4* H4 = (const float4*)(H + (size_t)node * DIM);
    const float* w1s = w1 + jbase;

    #define DT(i) float t##i = 0.0f;
    R24(DT)
    #undef DT

    #define F(i) t##i = fmaf(hk, wr[i], t##i);
    #pragma unroll 2
    for (int k4 = 0; k4 < 32; k4++) {
        float4 h4 = H4[k4];
        { float hk = h4.x; const float* wr = w1s + (k4 * 4 + 0) * SHID; R24(F) }
        { float hk = h4.y; const float* wr = w1s + (k4 * 4 + 1) * SHID; R24(F) }
        { float hk = h4.z; const float* wr = w1s + (k4 * 4 + 2) * SHID; R24(F) }
        { float hk = h4.w; const float* wr = w1s + (k4 * 4 + 3) * SHID; R24(F) }
    }
    #undef F
    // note: wave 2, jj>=21 reads w1 row tails (next row / <=12B past end at
    // k=127, page-slack safe); those t's are garbage and masked below.

    // ---- layer 2: partial logits over this wave's j-slice ----
    #define DL(c) float lg##c = 0.0f;
    R10(DL)
    #undef DL
    #define L2(i) { \
        int jv = jbase + (i); \
        int jx = (jv < SHID) ? jv : (SHID - 1); \
        float tr = (jv < SHID) ? fmaxf(t##i + b1[jx], 0.0f) : 0.0f; \
        const float* w2r = w2 + jx * NC; \
        lg0 = fmaf(tr, w2r[0], lg0); lg1 = fmaf(tr, w2r[1], lg1); \
        lg2 = fmaf(tr, w2r[2], lg2); lg3 = fmaf(tr, w2r[3], lg3); \
        lg4 = fmaf(tr, w2r[4], lg4); lg5 = fmaf(tr, w2r[5], lg5); \
        lg6 = fmaf(tr, w2r[6], lg6); lg7 = fmaf(tr, w2r[7], lg7); \
        lg8 = fmaf(tr, w2r[8], lg8); lg9 = fmaf(tr, w2r[9], lg9); }
    R24(L2)
    #undef L2

    #define ST(c) red[(c) * 192 + wu * 64 + lane] = lg##c;
    R10(ST)
    #undef ST
    __syncthreads();

    if (wu == 0) {
        #define LD(c) float s##c = red[(c) * 192 + lane] + red[(c) * 192 + 64 + lane] \
                                 + red[(c) * 192 + 128 + lane] + b2[c];
        R10(LD)
        #undef LD
        float m = fmaxf(fmaxf(fmaxf(s0, s1), fmaxf(s2, s3)),
                        fmaxf(fmaxf(fmaxf(s4, s5), fmaxf(s6, s7)), fmaxf(s8, s9)));
        float e0 = expf(s0 - m), e1 = expf(s1 - m), e2 = expf(s2 - m),
              e3 = expf(s3 - m), e4 = expf(s4 - m), e5 = expf(s5 - m),
              e6 = expf(s6 - m), e7 = expf(s7 - m), e8 = expf(s8 - m),
              e9 = expf(s9 - m);
        float ssum = ((e0 + e1) + (e2 + e3)) + ((e4 + e5) + (e6 + e7)) + (e8 + e9);
        float inv = 1.0f / ssum;
        float2* Sp2 = (float2*)(S + (size_t)node * NC);
        Sp2[0] = make_float2(e0 * inv, e1 * inv);
        Sp2[1] = make_float2(e2 * inv, e3 * inv);
        Sp2[2] = make_float2(e4 * inv, e5 * inv);
        Sp2[3] = make_float2(e6 * inv, e7 * inv);
        Sp2[4] = make_float2(e8 * inv, e9 * inv);
    }
}

// ---------------- K2: fused E + tail (corr, pred1, sample, Q, fm, pred2) ----------------
// Block = graph, 512 threads = 4 node-quarters x 128 d. Named-scalar accums,
// LDS combine, then the verified tail runs on wave 0 off LDS-resident E.
__global__ __launch_bounds__(512, 2) void k_E_tail(
    const float* __restrict__ H, const float* __restrict__ S,
    const float* __restrict__ wf, const float* __restrict__ bf,
    const int* __restrict__ targets,
    const float* __restrict__ p1, const float* __restrict__ pb1,
    const float* __restrict__ p2, const float* __restrict__ pb2,
    const float* __restrict__ ci, const float* __restrict__ cr,
    float* __restrict__ E, float* __restrict__ pred1, float* __restrict__ pred2,
    float* __restrict__ ind, float* __restrict__ Q) {
    __shared__ float Sl[128 * NC];                 // padded to 128 node rows
    __shared__ float Epart[3 * 128 * NC];          // quarters 1..3 partials
    __shared__ __align__(16) float El[NC * ELPAD];
    __shared__ float fmbuf[NC];
    int g = blockIdx.x, tid = threadIdx.x;

    const float* Sg = S + (size_t)g * NPG * NC;
    for (int i = tid; i < 128 * NC; i += 512) Sl[i] = (i < NPG * NC) ? Sg[i] : 0.0f;
    __syncthreads();

    int q = tid >> 7;       // node quarter 0..3
    int d = tid & 127;
    const float* Hg = H + (size_t)g * NPG * DIM + d;

    #define DECLA(c) float a##c = 0.f;
    R10(DECLA)
    #undef DECLA
    int n0 = q * 32;
    #pragma unroll 8
    for (int i = 0; i < 32; i++) {
        int n = n0 + i;
        int nh = min(n, NPG - 1);               // rows 125..127 have S=0
        float h = Hg[(size_t)nh * DIM];
        #define ACC(c) a##c = fmaf(Sl[n * NC + c], h, a##c);
        R10(ACC)
        #undef ACC
    }
    if (q > 0) {
        float* ep = &Epart[(q - 1) * 128 * NC + d * NC];
        #define STP(c) ep[c] = a##c;
        R10(STP)
        #undef STP
    }
    __syncthreads();
    if (q == 0) {
        const float* e1p = &Epart[d * NC];
        const float* e2p = &Epart[128 * NC + d * NC];
        const float* e3p = &Epart[2 * 128 * NC + d * NC];
        float* Eo = E + (size_t)g * (NC * DIM) + d;
        #define CMB(c) { a##c += e1p[c] + e2p[c] + e3p[c]; \
                         El[c * ELPAD + d] = a##c; Eo[c * DIM] = a##c; }
        R10(CMB)
        #undef CMB
    }
    __syncthreads();

    const float2* wf2 = (const float2*)wf;
    int l = tid;
    int samp = 0;
    float corr_lf = 0.f;

    if (tid < 64) {
        // ---- corr: lane l<32 computes corr[i=l>>4][f=l&15] ----
        if (l < 32) {
            int i = l >> 4, f = l & 15;
            float a = ci[f], b = ci[NF + f];
            float mm = fmaxf(a, b);
            float ea = expf(a - mm), eb = expf(b - mm);
            float inter = expf(ci[i * NF + f] - mm) / (ea + eb);
            float mi = -1e30f;
            for (int j = 0; j < NF; j++) mi = fmaxf(mi, cr[i * NF + j]);
            float ri = 0.f;
            for (int j = 0; j < NF; j++) ri += expf(cr[i * NF + j] - mi);
            float intra = expf(cr[i * NF + f] - mi) / ri;
            corr_lf = inter * intra;
        }

        // ---- phase 1: pred1 + softmax + gumbel sample + ind ----
        float a0 = 0.f, a1 = 0.f;
        #pragma unroll
        for (int i = 0; i < 20; i++) {
            int idx = i * 64 + l;
            float e = El[(idx >> 7) * ELPAD + (idx & 127)];
            float2 w = wf2[idx];
            a0 = fmaf(e, w.x, a0);
            a1 = fmaf(e, w.y, a1);
        }
        #pragma unroll
        for (int off = 32; off > 0; off >>= 1) {
            a0 += __shfl_down(a0, off);
            a1 += __shfl_down(a1, off);
        }
        if (l == 0) {
            float y0 = a0 + bf[0], y1 = a1 + bf[1];
            pred1[g * 2] = y0;
            pred1[g * 2 + 1] = y1;
            float m = fmaxf(y0, y1);
            float e0 = expf(y0 - m), e1 = expf(y1 - m), s = e0 + e1;
            float p0 = e0 / s, pp1 = e1 / s;
            float g0 = gumbel_from_bits(random_bits_partitionable(2 * g));
            float g1 = gumbel_from_bits(random_bits_partitionable(2 * g + 1));
            float l0 = logf(p0 + 1e-12f) + g0;
            float l1 = logf(pp1 + 1e-12f) + g1;
            samp = (l1 > l0) ? 1 : 0;
            ind[g] = (samp == targets[g]) ? 1.0f : 0.0f;
        }
        samp = __shfl(samp, 0);

        // ---- phase 2: Q-MLP (128->8 relu ->16 softmax) + feature_mask ----
        if (l < 40) {
            int p = l >> 2, s = l & 3;
            float ua = pb1[2 * s], ub = pb1[2 * s + 1];
            const float4* E4 = (const float4*)&El[p * ELPAD];
            #pragma unroll 4
            for (int k4 = 0; k4 < 32; k4++) {
                float4 e4 = E4[k4];
                float es[4] = {e4.x, e4.y, e4.z, e4.w};
                #pragma unroll
                for (int kk = 0; kk < 4; kk++) {
                    int k = k4 * 4 + kk;
                    ua = fmaf(es[kk], p1[k * PHID + 2 * s], ua);
                    ub = fmaf(es[kk], p1[k * PHID + 2 * s + 1], ub);
                }
            }
            ua = fmaxf(ua, 0.f);
            ub = fmaxf(ub, 0.f);
            float v[NF];
            #pragma unroll
            for (int f = 0; f < NF; f++) {
                v[f] = pb2[f] * 0.25f;  // bias split: reduce over 4 lanes adds it once
                v[f] = fmaf(ua, p2[(2 * s) * NF + f], v[f]);
                v[f] = fmaf(ub, p2[(2 * s + 1) * NF + f], v[f]);
            }
            #pragma unroll
            for (int f = 0; f < NF; f++) {
                v[f] += __shfl_xor(v[f], 1);
                v[f] += __shfl_xor(v[f], 2);
            }
            float m = v[0];
            #pragma unroll
            for (int f = 1; f < NF; f++) m = fmaxf(m, v[f]);
            float ssum = 0.f, qv[NF];
            #pragma unroll
            for (int f = 0; f < NF; f++) { qv[f] = expf(v[f] - m); ssum += qv[f]; }
            float inv = 1.0f / ssum;
            #pragma unroll
            for (int f = 0; f < NF; f++) qv[f] *= inv;
            float* Qo = Q + ((size_t)g * NC + p) * NF;
            ((float4*)Qo)[s] = make_float4(qv[s * 4], qv[s * 4 + 1], qv[s * 4 + 2], qv[s * 4 + 3]);
            float fmv = 0.f;
            #pragma unroll
            for (int f = 0; f < NF; f++) {
                float cv = __shfl(corr_lf, samp * NF + f);
                fmv = fmaf(qv[f], cv, fmv);
            }
            if (s == 0) fmbuf[p] = fmv;
        }
    }
    __syncthreads();

    if (tid < 64) {
        // ---- phase 3: pred2 ----
        float b0 = 0.f, b1acc = 0.f;
        #pragma unroll
        for (int i = 0; i < 20; i++) {
            int idx = i * 64 + l;
            float e = El[(idx >> 7) * ELPAD + (idx & 127)] * fmbuf[idx >> 7];
            float2 w = wf2[idx];
            b0 = fmaf(e, w.x, b0);
            b1acc = fmaf(e, w.y, b1acc);
        }
        #pragma unroll
        for (int off = 32; off > 0; off >>= 1) {
            b0 += __shfl_down(b0, off);
            b1acc += __shfl_down(b1acc, off);
        }
        if (l == 0) {
            pred2[g * 2] = b0 + bf[0];
            pred2[g * 2 + 1] = b1acc + bf[1];
        }
    }
}

extern "C" void kernel_launch(void* const* d_in, const int* in_sizes, int n_in,
                              void* d_out, int out_size, void* d_ws, size_t ws_size,
                              hipStream_t stream) {
    const float* H       = (const float*)d_in[0];
    // d_in[1] = batch (implied by n/125, unused)
    const int*   targets = (const int*)d_in[2];
    const float* w1      = (const float*)d_in[3];
    const float* b1      = (const float*)d_in[4];
    const float* w2      = (const float*)d_in[5];
    const float* b2      = (const float*)d_in[6];
    const float* wf      = (const float*)d_in[7];
    const float* bf      = (const float*)d_in[8];
    const float* p1      = (const float*)d_in[9];
    const float* pb1     = (const float*)d_in[10];
    const float* p2      = (const float*)d_in[11];
    const float* pb2     = (const float*)d_in[12];
    const float* ci      = (const float*)d_in[13];
    const float* cr      = (const float*)d_in[14];

    float* out   = (float*)d_out;
    float* pred1 = out + OFF_PRED1;
    float* pred2 = out + OFF_PRED2;
    float* ind   = out + OFF_IND;
    float* S     = out + OFF_S;
    float* E     = out + OFF_E;
    float* Q     = out + OFF_Q;

    k_node_mlp<<<NN / 64, 192, 0, stream>>>(H, w1, b1, w2, b2, S);
    k_E_tail<<<NG, 512, 0, stream>>>(H, S, wf, bf, targets, p1, pb1, p2, pb2,
                                     ci, cr, E, pred1, pred2, ind, Q);
}